// Round 9
// baseline (65.303 us; speedup 1.0000x reference)
//
#include <hip/hip_runtime.h>

// Pool255: out = (1/8) * sum of 8 directional cumulative-max pools.
// x: [8,256,128,128] fp32. 1024 blocks (2 waves each), 2 images per block.
//
// Wave0 sweeps rows top-down computing dirs {(-1,0),(-1,-1),(-1,+1),(0,-1)};
// wave1 sweeps bottom-up in a COLUMN-MIRRORED view (lane l <-> col 127-2l):
// identical recurrences. Lane l owns 2 adjacent (view-)columns {2l,2l+1}.
// All shift-by-1 cross-lane ops are DPP wave_shr:1/wave_shl:1 (pure VALU,
// NEGF boundary via `old`). Phase 0 writes fp16x2 partials to LDS; lgkm-only
// barrier; phase 1 combines with the other wave's partial, NT-stores out.
//
// R9: depth-16 prefetch ring (Ga/Gb, 16-row blocks of two 8-sub-blocks) so
// every load has >=8 iterations of slack; per-sub-block restructure
// {stage 8 x-pairs -> issue 8 prefetches -> 8 INDEPENDENT row scans (ILP) ->
// short serial v/d/a section}; compile-time row stride RS=+-128 for
// immediate-offset addressing.

#define NPIX 16384
#define NEGF (-3.402823466e38f)

typedef __fp16 half2v __attribute__((ext_vector_type(2)));

// dst[l] = src[l -/+ 1]; invalid lanes get `oldv`.
template <int CTRL>
__device__ __forceinline__ float dpp_movf(float oldv, float src) {
  return __int_as_float(__builtin_amdgcn_update_dpp(
      __float_as_int(oldv), __float_as_int(src), CTRL, 0xf, 0xf, false));
}
#define WAVE_SHR1 0x138  // lane l reads lane l-1 (lane 0 -> old)
#define WAVE_SHL1 0x130  // lane l reads lane l+1 (lane 63 -> old)

// y = max(y, dpp_move(y)) ; masked/invalid lanes keep old=y (no-op)
#define DPP_MAXSTEP(y, ctrl, rmask)                                          \
  y = fmaxf(y, __int_as_float(__builtin_amdgcn_update_dpp(                   \
                 __float_as_int(y), __float_as_int(y), ctrl, rmask, 0xf,     \
                 false)))

// Barrier draining only LDS (lgkm) — global prefetches stay in flight.
__device__ __forceinline__ void lds_barrier() {
  asm volatile("s_waitcnt lgkmcnt(0)\n\ts_barrier" ::: "memory");
}

template <bool MIR, int PHASE, int RS>
__device__ __forceinline__ void sub8(float2 (&G)[8], const int tb,
                                     const float* __restrict__ base,
                                     float* __restrict__ oim, const int off,
                                     unsigned* __restrict__ part,
                                     const int slot, float& v0, float& v1,
                                     float& d0, float& d1, float& a0,
                                     float& a1) {
  // ---- stage the 8 x-pairs (loads were issued >=8 iterations ago) ----
  float xs0[8], xs1[8];
#pragma unroll
  for (int k = 0; k < 8; ++k) {
    const float2 xv = G[k];
    xs0[k] = MIR ? xv.y : xv.x;
    xs1[k] = MIR ? xv.x : xv.y;
  }
  // ---- issue the next 8 prefetches (rows tb+16..tb+23 in sweep order) ----
#pragma unroll
  for (int k = 0; k < 8; ++k) {
    int tp = tb + 16 + k;
    if (PHASE) tp = (tp < 128) ? tp : 127;  // clamp at image end (uniform)
    G[k] = *(const float2*)(base + (ptrdiff_t)tp * RS);
  }
  // ---- phase 1: issue the 8 partial reads early ----
  unsigned Qs[8];
  if (PHASE) {
#pragma unroll
    for (int k = 0; k < 8; ++k) {
      const int row = MIR ? 127 - (tb + k) : (tb + k);
      Qs[k] = part[(row << 6) + slot];
    }
  }
  // ---- 8 independent row scans (ILP to hide DPP chain latency) ----
  float yy[8], ss0[8];
#pragma unroll
  for (int k = 0; k < 8; ++k) {
    float y = fmaxf(xs0[k], xs1[k]);
    DPP_MAXSTEP(y, 0x111, 0xf);  // row_shr:1
    DPP_MAXSTEP(y, 0x112, 0xf);  // row_shr:2
    DPP_MAXSTEP(y, 0x114, 0xf);  // row_shr:4
    DPP_MAXSTEP(y, 0x118, 0xf);  // row_shr:8
    DPP_MAXSTEP(y, 0x142, 0xa);  // row_bcast15 -> rows 1,3
    DPP_MAXSTEP(y, 0x143, 0xc);  // row_bcast31 -> rows 2,3
    const float ex = dpp_movf<WAVE_SHR1>(NEGF, y);
    ss0[k] = fmaxf(ex, xs0[k]);
    yy[k] = y;
  }
  // ---- serial v/d/a recurrences + combine ----
#pragma unroll
  for (int k = 0; k < 8; ++k) {
    v0 = fmaxf(v0, xs0[k]);
    v1 = fmaxf(v1, xs1[k]);
    const float pd = dpp_movf<WAVE_SHR1>(NEGF, d1);
    const float nd0 = fmaxf(xs0[k], pd);
    const float nd1 = fmaxf(xs1[k], d0);
    d0 = nd0; d1 = nd1;
    const float pa = dpp_movf<WAVE_SHL1>(NEGF, a0);
    const float na1 = fmaxf(xs1[k], pa);
    const float na0 = fmaxf(xs0[k], a1);
    a0 = na0; a1 = na1;

    const float p0 = (v0 + d0) + (a0 + ss0[k]);
    const float p1 = (v1 + d1) + (a1 + yy[k]);
    const int row = MIR ? 127 - (tb + k) : (tb + k);
    if (!PHASE) {
      const half2v h = MIR ? __builtin_amdgcn_cvt_pkrtz(p1, p0)
                           : __builtin_amdgcn_cvt_pkrtz(p0, p1);
      part[(row << 6) + slot] = __builtin_bit_cast(unsigned, h);
    } else {
      const half2v hq = __builtin_bit_cast(half2v, Qs[k]);
      const float q0 = (float)(MIR ? hq.y : hq.x);
      const float q1 = (float)(MIR ? hq.x : hq.y);
      const float o0 = (p0 + q0) * 0.125f;
      const float o1 = (p1 + q1) * 0.125f;
      const float2 ov = MIR ? make_float2(o1, o0) : make_float2(o0, o1);
      __builtin_nontemporal_store(
          __builtin_bit_cast(unsigned long long, ov),
          (unsigned long long*)(oim + (row << 7) + off));
    }
  }
}

template <bool MIR>
__device__ __forceinline__ void run(const float* __restrict__ xim,
                                    float* __restrict__ oim,
                                    unsigned* __restrict__ part, const int l) {
  constexpr int RS = MIR ? -128 : 128;         // sweep row stride (floats)
  const int off = MIR ? (63 - l) * 2 : l * 2;  // float index of the col pair
  const int slot = MIR ? (63 - l) : l;         // u32 slot in a part row
  const float* __restrict__ base = xim + off + (MIR ? 127 * 128 : 0);

  float v0 = NEGF, v1 = NEGF, d0 = NEGF, d1 = NEGF, a0 = NEGF, a1 = NEGF;

  // prologue: fill the 16-deep ring (sweep rows 0..15)
  float2 Ga[8], Gb[8];
#pragma unroll
  for (int k = 0; k < 8; ++k) Ga[k] = *(const float2*)(base + (ptrdiff_t)k * RS);
#pragma unroll
  for (int k = 0; k < 8; ++k) Gb[k] = *(const float2*)(base + (ptrdiff_t)(8 + k) * RS);

  // ---- phase 0: sweep rows 0..63, write fp16x2 partials ----
#pragma unroll 1
  for (int tb = 0; tb < 64; tb += 16) {
    sub8<MIR, 0, RS>(Ga, tb, base, oim, off, part, slot, v0, v1, d0, d1, a0, a1);
    sub8<MIR, 0, RS>(Gb, tb + 8, base, oim, off, part, slot, v0, v1, d0, d1, a0, a1);
  }

  lds_barrier();  // partials visible; global prefetches stay in flight

  // ---- phase 1: sweep rows 64..127, combine + NT-store ----
#pragma unroll 1
  for (int tb = 64; tb < 128; tb += 16) {
    sub8<MIR, 1, RS>(Ga, tb, base, oim, off, part, slot, v0, v1, d0, d1, a0, a1);
    sub8<MIR, 1, RS>(Gb, tb + 8, base, oim, off, part, slot, v0, v1, d0, d1, a0, a1);
  }
}

__global__ __launch_bounds__(128) void pool255_sweep(
    const float* __restrict__ x, float* __restrict__ out, int n_img) {
  __shared__ unsigned part[NPIX / 2];  // fp16x2, 32 KB
  const int l = threadIdx.x & 63;
  for (int img = blockIdx.x; img < n_img; img += gridDim.x) {
    const float* __restrict__ xim = x + (size_t)img * NPIX;
    float* __restrict__ oim = out + (size_t)img * NPIX;
    if (threadIdx.x < 64)
      run<false>(xim, oim, part, l);
    else
      run<true>(xim, oim, part, l);
    lds_barrier();  // protect part[] reuse across images
  }
}

extern "C" void kernel_launch(void* const* d_in, const int* in_sizes, int n_in,
                              void* d_out, int out_size, void* d_ws,
                              size_t ws_size, hipStream_t stream) {
  const float* x = (const float*)d_in[0];
  float* out = (float*)d_out;
  const int n_img = in_sizes[0] / NPIX;  // 8*256 = 2048
  const int grid = (n_img < 1024) ? n_img : 1024;  // 2 images/block, balanced
  pool255_sweep<<<grid, 128, 0, stream>>>(x, out, n_img);
}